// Round 4
// baseline (176.749 us; speedup 1.0000x reference)
//
#include <hip/hip_runtime.h>

#define NN   4096
#define FIN  512
#define FOUT 256
#define ALPHA 0.2f

typedef __attribute__((ext_vector_type(8))) short short8;
typedef __attribute__((ext_vector_type(4))) float f32x4;
typedef unsigned short u16;

__device__ __forceinline__ u16 f2bf(float x) {   // round-to-nearest-even
    union { float f; unsigned u; } v; v.f = x;
    unsigned r = v.u + 0x7FFF + ((v.u >> 16) & 1);
    return (u16)(r >> 16);
}

// ---------------- Kernel 0: Wt[f][k] bf16 = transpose(W [k][f] fp32) ----------------
// Also zeroes fs/fd for k_proj's atomic accumulation (32 blk x 256 thr = 8192 = 2*NN).
__global__ __launch_bounds__(256) void k_wt(const float* __restrict__ W,
                                            u16* __restrict__ Wt,
                                            float* __restrict__ fs,
                                            float* __restrict__ fd) {
    __shared__ float s[64 * 65];
    const int t  = threadIdx.x;
    const int g  = (blockIdx.y * gridDim.x + blockIdx.x) * 256 + t;
    if (g < NN) fs[g] = 0.f; else fd[g - NN] = 0.f;
    const int f0 = blockIdx.x * 64;
    const int k0 = blockIdx.y * 64;
    #pragma unroll
    for (int p = 0; p < 4; ++p) {
        int q = t + 256 * p, rr = q >> 4, cc = q & 15;
        float4 w4 = *(const float4*)&W[(size_t)(k0 + rr) * FOUT + f0 + cc * 4];
        s[(cc * 4 + 0) * 65 + rr] = w4.x;
        s[(cc * 4 + 1) * 65 + rr] = w4.y;
        s[(cc * 4 + 2) * 65 + rr] = w4.z;
        s[(cc * 4 + 3) * 65 + rr] = w4.w;
    }
    __syncthreads();
    #pragma unroll
    for (int p = 0; p < 4; ++p) {
        int q = t + 256 * p, f = q >> 4, kg = q & 15;
        ushort4 o;
        o.x = f2bf(s[f * 65 + kg * 4 + 0]);
        o.y = f2bf(s[f * 65 + kg * 4 + 1]);
        o.z = f2bf(s[f * 65 + kg * 4 + 2]);
        o.w = f2bf(s[f * 65 + kg * 4 + 3]);
        *(ushort4*)&Wt[(size_t)(f0 + f) * FIN + k0 + kg * 4] = o;
    }
}

// ------- Kernel 1: proj -> whT bf16 tiles + f_src/f_dst partials -------
#define HS 520   // u16 LDS row stride (1040 B = 65*16, aligned)
__global__ __launch_bounds__(256) void k_proj(const float* __restrict__ h,
                                              const u16* __restrict__ Wt,
                                              const float* __restrict__ bias,
                                              const float* __restrict__ a1,
                                              const float* __restrict__ a2,
                                              u16* __restrict__ whT,
                                              float* __restrict__ fs,
                                              float* __restrict__ fd) {
    __shared__ u16 s_h[32 * HS];   // 32 rows x 512 k bf16
    const int t  = threadIdx.x;
    const int f0 = blockIdx.x * 64;
    const int i0 = blockIdx.y * 32;
    #pragma unroll
    for (int p = 0; p < 16; ++p) {
        int q = t + 256 * p, row = q >> 7, c4 = q & 127;
        float4 v = *(const float4*)&h[(size_t)(i0 + row) * FIN + c4 * 4];
        ushort4 o; o.x = f2bf(v.x); o.y = f2bf(v.y); o.z = f2bf(v.z); o.w = f2bf(v.w);
        *(ushort4*)&s_h[row * HS + c4 * 4] = o;
    }
    __syncthreads();
    const int w = t >> 6, l = t & 63, n = l & 15, quad = l >> 4;
    const int hh = w & 1, fh = w >> 1;
    f32x4 acc[2] = {{0.f,0.f,0.f,0.f},{0.f,0.f,0.f,0.f}};
    #pragma unroll
    for (int k0 = 0; k0 < FIN; k0 += 32) {
        short8 a = *(const short8*)&s_h[(hh * 16 + n) * HS + k0 + quad * 8];
        short8 b0 = *(const short8*)&Wt[(size_t)(f0 + fh * 32 + n) * FIN + k0 + quad * 8];
        short8 b1 = *(const short8*)&Wt[(size_t)(f0 + fh * 32 + 16 + n) * FIN + k0 + quad * 8];
        acc[0] = __builtin_amdgcn_mfma_f32_16x16x32_bf16(a, b0, acc[0], 0, 0, 0);
        acc[1] = __builtin_amdgcn_mfma_f32_16x16x32_bf16(a, b1, acc[1], 0, 0, 0);
    }
    const int fb = f0 + fh * 32 + n;
    const float bv0 = bias[fb],  bv1 = bias[fb + 16];
    const float a10 = a1[fb],    a11 = a1[fb + 16];
    const float a20 = a2[fb],    a21 = a2[fb + 16];
    u16* wt_tile = whT + (size_t)(i0 >> 5) * (FOUT * 32);
    float d1[4], d2[4];
    #pragma unroll
    for (int r = 0; r < 4; ++r) {
        const int ic = hh * 16 + quad * 4 + r;       // i - i0
        const float v0 = acc[0][r] + bv0;
        const float v1 = acc[1][r] + bv1;
        wt_tile[fb * 32 + ic]        = f2bf(v0);
        wt_tile[(fb + 16) * 32 + ic] = f2bf(v1);
        d1[r] = v0 * a10 + v1 * a11;
        d2[r] = v0 * a20 + v1 * a21;
    }
    #pragma unroll
    for (int m = 1; m < 16; m <<= 1) {
        #pragma unroll
        for (int r = 0; r < 4; ++r) {
            d1[r] += __shfl_xor(d1[r], m);
            d2[r] += __shfl_xor(d2[r], m);
        }
    }
    if (n == 0) {
        #pragma unroll
        for (int r = 0; r < 4; ++r) {
            const int i = i0 + hh * 16 + quad * 4 + r;
            atomicAdd(&fs[i], d1[r]);
            atomicAdd(&fd[i], d2[r]);
        }
    }
}

// ------ Kernel 2: F = exp(fd), H = exp(alpha*fd) (rank-1 softmax factorization) ------
__global__ __launch_bounds__(256) void k_exp(const float* __restrict__ fd,
                                             float* __restrict__ Fj,
                                             float* __restrict__ Hj) {
    const int g = blockIdx.x * 256 + threadIdx.x;
    float4 v = ((const float4*)fd)[g];
    float4 F, H;
    F.x = __expf(v.x); F.y = __expf(v.y); F.z = __expf(v.z); F.w = __expf(v.w);
    H.x = __expf(ALPHA * v.x); H.y = __expf(ALPHA * v.y);
    H.z = __expf(ALPHA * v.z); H.w = __expf(ALPHA * v.w);
    ((float4*)Fj)[g] = F;
    ((float4*)Hj)[g] = H;
}

// ------ Kernel 3: barrier-free fused mask+softmax-num + MFMA P@wh ------
// exp(leaky(fs_i+fd_j)) = (s>=0 ? E_i*F_j : G_i*H_j); branch test in exp-domain
// (F_j >= R_i, R_i = exp(-(fs_i+ab))) -- leaky is continuous at 0 so the rounded
// comparison is harmless. Each wave builds its A-frags IN REGISTERS in the exact
// MFMA layout (lane(n,quad) owns P[n][quad*8..+8] and P[n+16][...]): no LDS, no
// barriers, no setprio. Block = 4 free-running waves = f-quarters of 32 x jchunk.
#define BI 32
#define KJ 32
#define CJ 8    // j-chunks; must equal gridDim.y of k_attn
__global__ __launch_bounds__(256) void k_attn(const int* __restrict__ adj,
                                              const u16* __restrict__ whT,
                                              const float* __restrict__ fs,
                                              const float* __restrict__ Fj,
                                              const float* __restrict__ Hj,
                                              const float* __restrict__ ab,
                                              float* __restrict__ part,
                                              float* __restrict__ psum) {
    const int t = threadIdx.x;
    const int w = t >> 6, l = t & 63, n = l & 15, quad = l >> 4;
    const int i0 = blockIdx.x * BI;
    const int c  = blockIdx.y;
    const int jbeg = c * (NN / CJ), jend = jbeg + (NN / CJ);
    const int fw  = w * 64;
    const int jq8 = quad * 8;

    const float abv = ab[0];
    const float s0 = fs[i0 + n] + abv;
    const float s1 = fs[i0 + 16 + n] + abv;
    const float E0 = __expf(s0), G0 = __expf(ALPHA * s0), R0 = __expf(-s0);
    const float E1 = __expf(s1), G1 = __expf(ALPHA * s1), R1 = __expf(-s1);

    f32x4 acc[2][4] = {{{0.f,0.f,0.f,0.f},{0.f,0.f,0.f,0.f},{0.f,0.f,0.f,0.f},{0.f,0.f,0.f,0.f}},
                       {{0.f,0.f,0.f,0.f},{0.f,0.f,0.f,0.f},{0.f,0.f,0.f,0.f},{0.f,0.f,0.f,0.f}}};
    float rs0 = 0.f, rs1 = 0.f;

    const size_t ar0 = (size_t)(i0 + n) * NN;
    const size_t ar1 = (size_t)(i0 + 16 + n) * NN;

    // depth-1 prefetch of adj (the only HBM stream)
    int4 c0a = *(const int4*)&adj[ar0 + jbeg + jq8];
    int4 c0b = *(const int4*)&adj[ar0 + jbeg + jq8 + 4];
    int4 c1a = *(const int4*)&adj[ar1 + jbeg + jq8];
    int4 c1b = *(const int4*)&adj[ar1 + jbeg + jq8 + 4];

#define PEL(FV, HV, AV, E, G, R, OO, IDX, RS) do {            \
        float _mi = (FV) >= (R) ? (E) : (G);                  \
        float _mj = (FV) >= (R) ? (FV) : (HV);                \
        float _p  = ((AV) > 0) ? _mi * _mj : 0.f;             \
        OO.e[IDX] = f2bf(_p); RS += _p; } while (0)

    #pragma unroll 2
    for (int j0 = jbeg; j0 < jend; j0 += KJ) {
        // ---- B-frags for this K-step (L2-hot whT, issued early) ----
        const u16* tb = whT + (size_t)(j0 >> 5) * (FOUT * 32) + quad * 8;
        short8 b[4];
        #pragma unroll
        for (int u = 0; u < 4; ++u)
            b[u] = *(const short8*)&tb[(fw + u * 16 + n) * 32];
        // ---- F/H for this K-step (L1 broadcast: 4 distinct addrs/wave) ----
        float4 Fa = *(const float4*)&Fj[j0 + jq8];
        float4 Fb = *(const float4*)&Fj[j0 + jq8 + 4];
        float4 Ha = *(const float4*)&Hj[j0 + jq8];
        float4 Hb = *(const float4*)&Hj[j0 + jq8 + 4];
        // ---- consume prefetched adj; issue next K-step's ----
        int4 a0a = c0a, a0b = c0b, a1a = c1a, a1b = c1b;
        if (j0 + KJ < jend) {
            c0a = *(const int4*)&adj[ar0 + j0 + KJ + jq8];
            c0b = *(const int4*)&adj[ar0 + j0 + KJ + jq8 + 4];
            c1a = *(const int4*)&adj[ar1 + j0 + KJ + jq8];
            c1b = *(const int4*)&adj[ar1 + j0 + KJ + jq8 + 4];
        }
        // ---- build A-frags in registers (rowgroups n and n+16) ----
        union { short8 v; u16 e[8]; } o0, o1;
        PEL(Fa.x, Ha.x, a0a.x, E0, G0, R0, o0, 0, rs0);
        PEL(Fa.y, Ha.y, a0a.y, E0, G0, R0, o0, 1, rs0);
        PEL(Fa.z, Ha.z, a0a.z, E0, G0, R0, o0, 2, rs0);
        PEL(Fa.w, Ha.w, a0a.w, E0, G0, R0, o0, 3, rs0);
        PEL(Fb.x, Hb.x, a0b.x, E0, G0, R0, o0, 4, rs0);
        PEL(Fb.y, Hb.y, a0b.y, E0, G0, R0, o0, 5, rs0);
        PEL(Fb.z, Hb.z, a0b.z, E0, G0, R0, o0, 6, rs0);
        PEL(Fb.w, Hb.w, a0b.w, E0, G0, R0, o0, 7, rs0);
        PEL(Fa.x, Ha.x, a1a.x, E1, G1, R1, o1, 0, rs1);
        PEL(Fa.y, Ha.y, a1a.y, E1, G1, R1, o1, 1, rs1);
        PEL(Fa.z, Ha.z, a1a.z, E1, G1, R1, o1, 2, rs1);
        PEL(Fa.w, Ha.w, a1a.w, E1, G1, R1, o1, 3, rs1);
        PEL(Fb.x, Hb.x, a1b.x, E1, G1, R1, o1, 4, rs1);
        PEL(Fb.y, Hb.y, a1b.y, E1, G1, R1, o1, 5, rs1);
        PEL(Fb.z, Hb.z, a1b.z, E1, G1, R1, o1, 6, rs1);
        PEL(Fb.w, Hb.w, a1b.w, E1, G1, R1, o1, 7, rs1);
        // ---- MFMA: 32i x 64f per wave, K=32 ----
        #pragma unroll
        for (int u = 0; u < 4; ++u) {
            acc[0][u] = __builtin_amdgcn_mfma_f32_16x16x32_bf16(o0.v, b[u], acc[0][u], 0, 0, 0);
            acc[1][u] = __builtin_amdgcn_mfma_f32_16x16x32_bf16(o1.v, b[u], acc[1][u], 0, 0, 0);
        }
    }
#undef PEL
    // ---- denominators: sum over quads (lane bits 4,5); all 4 waves identical, w0 writes ----
    rs0 += __shfl_xor(rs0, 16); rs0 += __shfl_xor(rs0, 32);
    rs1 += __shfl_xor(rs1, 16); rs1 += __shfl_xor(rs1, 32);
    if (w == 0 && quad == 0) {
        psum[(size_t)c * NN + i0 + n]      = rs0;
        psum[(size_t)c * NN + i0 + 16 + n] = rs1;
    }
    // ---- partial numerators ----
    float* pc = part + ((size_t)c * NN + i0) * FOUT;
    #pragma unroll
    for (int hf = 0; hf < 2; ++hf)
        #pragma unroll
        for (int u = 0; u < 4; ++u)
            #pragma unroll
            for (int r = 0; r < 4; ++r)
                pc[(size_t)(hf * 16 + quad * 4 + r) * FOUT + fw + u * 16 + n] = acc[hf][u][r];
}

// ------ Kernel 4: combine partials, normalize, elu ------
__global__ __launch_bounds__(256) void k_fin(const float* __restrict__ part,
                                             const float* __restrict__ psum,
                                             float* __restrict__ out, int C) {
    const int g = blockIdx.x * 256 + threadIdx.x;
    const int i = g >> 6;
    const size_t s4 = (size_t)NN * FOUT / 4;
    float4 a = ((const float4*)part)[g];
    float s = psum[i];
    for (int c = 1; c < C; ++c) {
        float4 bb = ((const float4*)part)[g + (size_t)c * s4];
        a.x += bb.x; a.y += bb.y; a.z += bb.z; a.w += bb.w;
        s += psum[(size_t)c * NN + i];
    }
    const float inv = 1.0f / s;
    a.x *= inv; a.y *= inv; a.z *= inv; a.w *= inv;
    a.x = a.x > 0.f ? a.x : __expf(a.x) - 1.f;
    a.y = a.y > 0.f ? a.y : __expf(a.y) - 1.f;
    a.z = a.z > 0.f ? a.z : __expf(a.z) - 1.f;
    a.w = a.w > 0.f ? a.w : __expf(a.w) - 1.f;
    ((float4*)out)[g] = a;
}

extern "C" void kernel_launch(void* const* d_in, const int* in_sizes, int n_in,
                              void* d_out, int out_size, void* d_ws, size_t ws_size,
                              hipStream_t stream) {
    const int*   adj = (const int*)  d_in[0];
    const float* h   = (const float*)d_in[1];
    const float* W   = (const float*)d_in[2];
    const float* b   = (const float*)d_in[3];
    const float* a1  = (const float*)d_in[4];
    const float* a2  = (const float*)d_in[5];
    const float* ab  = (const float*)d_in[6];
    float* out = (float*)d_out;

    const int C = CJ;   // compile-time j-chunking (k_attn assumes gridDim.y == CJ)

    float* fs   = (float*)d_ws;
    float* fd   = fs + NN;
    float* Fjv  = fd + NN;
    float* Hjv  = Fjv + NN;
    float* psum = Hjv + NN;
    float* part = psum + (size_t)C * NN;
    u16*   Wt   = (u16*)(part + (size_t)C * NN * FOUT);
    u16*   whT  = Wt + (size_t)FOUT * FIN;

    k_wt  <<<dim3(FOUT / 64, FIN / 64), 256, 0, stream>>>(W, Wt, fs, fd);
    k_proj<<<dim3(FOUT / 64, NN / 32), 256, 0, stream>>>(h, Wt, b, a1, a2, whT, fs, fd);
    k_exp <<<NN / 1024, 256, 0, stream>>>(fd, Fjv, Hjv);
    k_attn<<<dim3(NN / BI, C), 256, 0, stream>>>(adj, whT, fs, Fjv, Hjv, ab, part, psum);
    k_fin <<<(NN * FOUT / 4) / 256, 256, 0, stream>>>(part, psum, out, C);
}

// Round 5
// 171.047 us; speedup vs baseline: 1.0333x; 1.0333x over previous
//
#include <hip/hip_runtime.h>

#define NN   4096
#define FIN  512
#define FOUT 256
#define ALPHA 0.2f

typedef __attribute__((ext_vector_type(8))) short short8;
typedef __attribute__((ext_vector_type(4))) float f32x4;
typedef unsigned short u16;
typedef unsigned int u32;

__device__ __forceinline__ u16 f2bf(float x) {   // round-to-nearest-even
    union { float f; unsigned u; } v; v.f = x;
    unsigned r = v.u + 0x7FFF + ((v.u >> 16) & 1);
    return (u16)(r >> 16);
}

// ---------------- Kernel 0: Wt[f][k] bf16 = transpose(W [k][f] fp32) ----------------
// Also zeroes fs/fd for k_proj's atomic accumulation (32 blk x 256 thr = 8192 = 2*NN).
__global__ __launch_bounds__(256) void k_wt(const float* __restrict__ W,
                                            u16* __restrict__ Wt,
                                            float* __restrict__ fs,
                                            float* __restrict__ fd) {
    __shared__ float s[64 * 65];
    const int t  = threadIdx.x;
    const int g  = (blockIdx.y * gridDim.x + blockIdx.x) * 256 + t;
    if (g < NN) fs[g] = 0.f; else fd[g - NN] = 0.f;
    const int f0 = blockIdx.x * 64;
    const int k0 = blockIdx.y * 64;
    #pragma unroll
    for (int p = 0; p < 4; ++p) {
        int q = t + 256 * p, rr = q >> 4, cc = q & 15;
        float4 w4 = *(const float4*)&W[(size_t)(k0 + rr) * FOUT + f0 + cc * 4];
        s[(cc * 4 + 0) * 65 + rr] = w4.x;
        s[(cc * 4 + 1) * 65 + rr] = w4.y;
        s[(cc * 4 + 2) * 65 + rr] = w4.z;
        s[(cc * 4 + 3) * 65 + rr] = w4.w;
    }
    __syncthreads();
    #pragma unroll
    for (int p = 0; p < 4; ++p) {
        int q = t + 256 * p, f = q >> 4, kg = q & 15;
        ushort4 o;
        o.x = f2bf(s[f * 65 + kg * 4 + 0]);
        o.y = f2bf(s[f * 65 + kg * 4 + 1]);
        o.z = f2bf(s[f * 65 + kg * 4 + 2]);
        o.w = f2bf(s[f * 65 + kg * 4 + 3]);
        *(ushort4*)&Wt[(size_t)(f0 + f) * FIN + k0 + kg * 4] = o;
    }
}

// ------ Kernel 1: adj (64 MB int32) -> bitmask (2 MB): bit j of row i = adj[i][j]>0 ------
// One wave per row; 16 outer iters x 4 independent coalesced loads (ILP to cover HBM).
__global__ __launch_bounds__(256) void k_bits(const int* __restrict__ adj,
                                              unsigned long long* __restrict__ bits) {
    const int t = threadIdx.x, l = t & 63;
    const int row = blockIdx.x * 4 + (t >> 6);
    const size_t base = (size_t)row * NN;
    #pragma unroll 4
    for (int o = 0; o < 16; ++o) {
        unsigned long long b0 = __ballot(adj[base + (o * 4 + 0) * 64 + l] > 0);
        unsigned long long b1 = __ballot(adj[base + (o * 4 + 1) * 64 + l] > 0);
        unsigned long long b2 = __ballot(adj[base + (o * 4 + 2) * 64 + l] > 0);
        unsigned long long b3 = __ballot(adj[base + (o * 4 + 3) * 64 + l] > 0);
        if (l == 0) {
            unsigned long long* d = bits + (size_t)row * 64 + o * 4;
            d[0] = b0; d[1] = b1; d[2] = b2; d[3] = b3;
        }
    }
}

// ------- Kernel 2: proj -> whT bf16 tiles + f_src/f_dst partials -------
#define HS 520   // u16 LDS row stride (1040 B = 65*16, aligned)
__global__ __launch_bounds__(256) void k_proj(const float* __restrict__ h,
                                              const u16* __restrict__ Wt,
                                              const float* __restrict__ bias,
                                              const float* __restrict__ a1,
                                              const float* __restrict__ a2,
                                              u16* __restrict__ whT,
                                              float* __restrict__ fs,
                                              float* __restrict__ fd) {
    __shared__ u16 s_h[32 * HS];   // 32 rows x 512 k bf16
    const int t  = threadIdx.x;
    const int f0 = blockIdx.x * 64;
    const int i0 = blockIdx.y * 32;
    #pragma unroll
    for (int p = 0; p < 16; ++p) {
        int q = t + 256 * p, row = q >> 7, c4 = q & 127;
        float4 v = *(const float4*)&h[(size_t)(i0 + row) * FIN + c4 * 4];
        ushort4 o; o.x = f2bf(v.x); o.y = f2bf(v.y); o.z = f2bf(v.z); o.w = f2bf(v.w);
        *(ushort4*)&s_h[row * HS + c4 * 4] = o;
    }
    __syncthreads();
    const int w = t >> 6, l = t & 63, n = l & 15, quad = l >> 4;
    const int hh = w & 1, fh = w >> 1;
    f32x4 acc[2] = {{0.f,0.f,0.f,0.f},{0.f,0.f,0.f,0.f}};
    #pragma unroll
    for (int k0 = 0; k0 < FIN; k0 += 32) {
        short8 a = *(const short8*)&s_h[(hh * 16 + n) * HS + k0 + quad * 8];
        short8 b0 = *(const short8*)&Wt[(size_t)(f0 + fh * 32 + n) * FIN + k0 + quad * 8];
        short8 b1 = *(const short8*)&Wt[(size_t)(f0 + fh * 32 + 16 + n) * FIN + k0 + quad * 8];
        acc[0] = __builtin_amdgcn_mfma_f32_16x16x32_bf16(a, b0, acc[0], 0, 0, 0);
        acc[1] = __builtin_amdgcn_mfma_f32_16x16x32_bf16(a, b1, acc[1], 0, 0, 0);
    }
    const int fb = f0 + fh * 32 + n;
    const float bv0 = bias[fb],  bv1 = bias[fb + 16];
    const float a10 = a1[fb],    a11 = a1[fb + 16];
    const float a20 = a2[fb],    a21 = a2[fb + 16];
    u16* wt_tile = whT + (size_t)(i0 >> 5) * (FOUT * 32);
    float d1[4], d2[4];
    #pragma unroll
    for (int r = 0; r < 4; ++r) {
        const int ic = hh * 16 + quad * 4 + r;       // i - i0
        const float v0 = acc[0][r] + bv0;
        const float v1 = acc[1][r] + bv1;
        wt_tile[fb * 32 + ic]        = f2bf(v0);
        wt_tile[(fb + 16) * 32 + ic] = f2bf(v1);
        d1[r] = v0 * a10 + v1 * a11;
        d2[r] = v0 * a20 + v1 * a21;
    }
    #pragma unroll
    for (int m = 1; m < 16; m <<= 1) {
        #pragma unroll
        for (int r = 0; r < 4; ++r) {
            d1[r] += __shfl_xor(d1[r], m);
            d2[r] += __shfl_xor(d2[r], m);
        }
    }
    if (n == 0) {
        #pragma unroll
        for (int r = 0; r < 4; ++r) {
            const int i = i0 + hh * 16 + quad * 4 + r;
            atomicAdd(&fs[i], d1[r]);
            atomicAdd(&fd[i], d2[r]);
        }
    }
}

// ------ Kernel 3: F = exp(fd), H = exp(alpha*fd) (rank-1 softmax factorization) ------
__global__ __launch_bounds__(256) void k_exp(const float* __restrict__ fd,
                                             float* __restrict__ Fj,
                                             float* __restrict__ Hj) {
    const int g = blockIdx.x * 256 + threadIdx.x;
    float4 v = ((const float4*)fd)[g];
    float4 F, H;
    F.x = __expf(v.x); F.y = __expf(v.y); F.z = __expf(v.z); F.w = __expf(v.w);
    H.x = __expf(ALPHA * v.x); H.y = __expf(ALPHA * v.y);
    H.z = __expf(ALPHA * v.z); H.w = __expf(ALPHA * v.w);
    ((float4*)Fj)[g] = F;
    ((float4*)Hj)[g] = H;
}

// ------ Kernel 4: barrier-free fused mask+softmax-num + MFMA P@wh (L2-only loop) ------
// exp(leaky(fs_i+fd_j)) = max(E_i*F_j, G_i*H_j)  [s>=0: e^s >= e^as picks e^s;
// s<0: e^as > e^s picks e^as -- always the correct branch, no compare needed].
// adj replaced by the 2 MB bitmask (L2-hot): the loop has NO HBM dependency.
// Each wave builds A-frags in registers in exact MFMA layout; no LDS, no barriers.
#define BI 32
#define CJ 8    // j-chunks; must equal gridDim.y of k_attn
__global__ __launch_bounds__(256) void k_attn(const u32* __restrict__ bits,
                                              const u16* __restrict__ whT,
                                              const float* __restrict__ fs,
                                              const float* __restrict__ Fj,
                                              const float* __restrict__ Hj,
                                              const float* __restrict__ ab,
                                              float* __restrict__ part,
                                              float* __restrict__ psum) {
    const int t = threadIdx.x;
    const int w = t >> 6, l = t & 63, n = l & 15, quad = l >> 4;
    const int i0 = blockIdx.x * BI;
    const int c  = blockIdx.y;
    const int jbeg = c * (NN / CJ), jend = jbeg + (NN / CJ);
    const int fw  = w * 64;
    const int jq8 = quad * 8;

    const float abv = ab[0];
    const float s0 = fs[i0 + n] + abv;
    const float s1 = fs[i0 + 16 + n] + abv;
    const float E0 = __expf(s0), G0 = __expf(ALPHA * s0);
    const float E1 = __expf(s1), G1 = __expf(ALPHA * s1);

    f32x4 acc[2][4] = {{{0.f,0.f,0.f,0.f},{0.f,0.f,0.f,0.f},{0.f,0.f,0.f,0.f},{0.f,0.f,0.f,0.f}},
                       {{0.f,0.f,0.f,0.f},{0.f,0.f,0.f,0.f},{0.f,0.f,0.f,0.f},{0.f,0.f,0.f,0.f}}};
    float rs0 = 0.f, rs1 = 0.f;

    const u32* B0 = bits + (size_t)(i0 + n) * 128;        // u32 words per row
    const u32* B1 = bits + (size_t)(i0 + 16 + n) * 128;
    uint4 m0 = *(const uint4*)&B0[jbeg >> 5];             // bits for next 4 K-steps
    uint4 m1 = *(const uint4*)&B1[jbeg >> 5];

#define PEL(FV, HV, BW, K, E, G, OO, IDX, RS) do {            \
        float _p = fmaxf((E) * (FV), (G) * (HV));             \
        _p = ((BW) & (1u << (K))) ? _p : 0.f;                 \
        OO.e[IDX] = f2bf(_p); RS += _p; } while (0)

    for (int jb = jbeg; jb < jend; jb += 128) {
        const uint4 cm0 = m0, cm1 = m1;
        if (jb + 128 < jend) {                 // prefetch next bit-block (L2)
            m0 = *(const uint4*)&B0[(jb + 128) >> 5];
            m1 = *(const uint4*)&B1[(jb + 128) >> 5];
        }
        #pragma unroll
        for (int s = 0; s < 4; ++s) {          // 4 K-steps of 32 j, static bit-word select
            const int j0 = jb + s * 32;
            const u32 bw0 = (s == 0 ? cm0.x : s == 1 ? cm0.y : s == 2 ? cm0.z : cm0.w) >> jq8;
            const u32 bw1 = (s == 0 ? cm1.x : s == 1 ? cm1.y : s == 2 ? cm1.z : cm1.w) >> jq8;
            // B-frags (L2-hot whT), issued first
            const u16* tb = whT + (size_t)(j0 >> 5) * (FOUT * 32) + quad * 8;
            short8 b[4];
            #pragma unroll
            for (int u = 0; u < 4; ++u)
                b[u] = *(const short8*)&tb[(fw + u * 16 + n) * 32];
            // F/H (L1 broadcast)
            float4 Fa = *(const float4*)&Fj[j0 + jq8];
            float4 Fb = *(const float4*)&Fj[j0 + jq8 + 4];
            float4 Ha = *(const float4*)&Hj[j0 + jq8];
            float4 Hb = *(const float4*)&Hj[j0 + jq8 + 4];
            // A-frags in registers (rowgroups n and n+16)
            union { short8 v; u16 e[8]; } o0, o1;
            PEL(Fa.x, Ha.x, bw0, 0, E0, G0, o0, 0, rs0);
            PEL(Fa.y, Ha.y, bw0, 1, E0, G0, o0, 1, rs0);
            PEL(Fa.z, Ha.z, bw0, 2, E0, G0, o0, 2, rs0);
            PEL(Fa.w, Ha.w, bw0, 3, E0, G0, o0, 3, rs0);
            PEL(Fb.x, Hb.x, bw0, 4, E0, G0, o0, 4, rs0);
            PEL(Fb.y, Hb.y, bw0, 5, E0, G0, o0, 5, rs0);
            PEL(Fb.z, Hb.z, bw0, 6, E0, G0, o0, 6, rs0);
            PEL(Fb.w, Hb.w, bw0, 7, E0, G0, o0, 7, rs0);
            PEL(Fa.x, Ha.x, bw1, 0, E1, G1, o1, 0, rs1);
            PEL(Fa.y, Ha.y, bw1, 1, E1, G1, o1, 1, rs1);
            PEL(Fa.z, Ha.z, bw1, 2, E1, G1, o1, 2, rs1);
            PEL(Fa.w, Ha.w, bw1, 3, E1, G1, o1, 3, rs1);
            PEL(Fb.x, Hb.x, bw1, 4, E1, G1, o1, 4, rs1);
            PEL(Fb.y, Hb.y, bw1, 5, E1, G1, o1, 5, rs1);
            PEL(Fb.z, Hb.z, bw1, 6, E1, G1, o1, 6, rs1);
            PEL(Fb.w, Hb.w, bw1, 7, E1, G1, o1, 7, rs1);
            // MFMA: 32i x 64f per wave, K=32
            #pragma unroll
            for (int u = 0; u < 4; ++u) {
                acc[0][u] = __builtin_amdgcn_mfma_f32_16x16x32_bf16(o0.v, b[u], acc[0][u], 0, 0, 0);
                acc[1][u] = __builtin_amdgcn_mfma_f32_16x16x32_bf16(o1.v, b[u], acc[1][u], 0, 0, 0);
            }
        }
    }
#undef PEL
    // ---- denominators: sum over quads (lane bits 4,5); all 4 waves identical, w0 writes ----
    rs0 += __shfl_xor(rs0, 16); rs0 += __shfl_xor(rs0, 32);
    rs1 += __shfl_xor(rs1, 16); rs1 += __shfl_xor(rs1, 32);
    if (w == 0 && quad == 0) {
        psum[(size_t)c * NN + i0 + n]      = rs0;
        psum[(size_t)c * NN + i0 + 16 + n] = rs1;
    }
    // ---- partial numerators ----
    float* pc = part + ((size_t)c * NN + i0) * FOUT;
    #pragma unroll
    for (int hf = 0; hf < 2; ++hf)
        #pragma unroll
        for (int u = 0; u < 4; ++u)
            #pragma unroll
            for (int r = 0; r < 4; ++r)
                pc[(size_t)(hf * 16 + quad * 4 + r) * FOUT + fw + u * 16 + n] = acc[hf][u][r];
}

// ------ Kernel 5: combine partials, normalize, elu ------
__global__ __launch_bounds__(256) void k_fin(const float* __restrict__ part,
                                             const float* __restrict__ psum,
                                             float* __restrict__ out, int C) {
    const int g = blockIdx.x * 256 + threadIdx.x;
    const int i = g >> 6;
    const size_t s4 = (size_t)NN * FOUT / 4;
    float4 a = ((const float4*)part)[g];
    float s = psum[i];
    for (int c = 1; c < C; ++c) {
        float4 bb = ((const float4*)part)[g + (size_t)c * s4];
        a.x += bb.x; a.y += bb.y; a.z += bb.z; a.w += bb.w;
        s += psum[(size_t)c * NN + i];
    }
    const float inv = 1.0f / s;
    a.x *= inv; a.y *= inv; a.z *= inv; a.w *= inv;
    a.x = a.x > 0.f ? a.x : __expf(a.x) - 1.f;
    a.y = a.y > 0.f ? a.y : __expf(a.y) - 1.f;
    a.z = a.z > 0.f ? a.z : __expf(a.z) - 1.f;
    a.w = a.w > 0.f ? a.w : __expf(a.w) - 1.f;
    ((float4*)out)[g] = a;
}

extern "C" void kernel_launch(void* const* d_in, const int* in_sizes, int n_in,
                              void* d_out, int out_size, void* d_ws, size_t ws_size,
                              hipStream_t stream) {
    const int*   adj = (const int*)  d_in[0];
    const float* h   = (const float*)d_in[1];
    const float* W   = (const float*)d_in[2];
    const float* b   = (const float*)d_in[3];
    const float* a1  = (const float*)d_in[4];
    const float* a2  = (const float*)d_in[5];
    const float* ab  = (const float*)d_in[6];
    float* out = (float*)d_out;

    const int C = CJ;   // compile-time j-chunking (k_attn assumes gridDim.y == CJ)

    float* fs   = (float*)d_ws;
    float* fd   = fs + NN;
    float* Fjv  = fd + NN;
    float* Hjv  = Fjv + NN;
    float* psum = Hjv + NN;
    float* part = psum + (size_t)C * NN;
    u16*   Wt   = (u16*)(part + (size_t)C * NN * FOUT);
    u16*   whT  = Wt + (size_t)FOUT * FIN;
    unsigned long long* bits = (unsigned long long*)(whT + (size_t)NN * FOUT);

    k_wt  <<<dim3(FOUT / 64, FIN / 64), 256, 0, stream>>>(W, Wt, fs, fd);
    k_bits<<<NN / 4, 256, 0, stream>>>(adj, bits);
    k_proj<<<dim3(FOUT / 64, NN / 32), 256, 0, stream>>>(h, Wt, b, a1, a2, whT, fs, fd);
    k_exp <<<NN / 1024, 256, 0, stream>>>(fd, Fjv, Hjv);
    k_attn<<<dim3(NN / BI, C), 256, 0, stream>>>((const u32*)bits, whT, fs, Fjv, Hjv, ab, part, psum);
    k_fin <<<(NN * FOUT / 4) / 256, 256, 0, stream>>>(part, psum, out, C);
}

// Round 7
// 167.840 us; speedup vs baseline: 1.0531x; 1.0191x over previous
//
#include <hip/hip_runtime.h>

#define NN   4096
#define FIN  512
#define FOUT 256
#define ALPHA 0.2f

typedef __attribute__((ext_vector_type(8))) short short8;
typedef __attribute__((ext_vector_type(4))) float f32x4;
typedef unsigned short u16;
typedef unsigned int u32;
typedef unsigned long long u64;

__device__ __forceinline__ u16 f2bf(float x) {   // round-to-nearest-even
    union { float f; unsigned u; } v; v.f = x;
    unsigned r = v.u + 0x7FFF + ((v.u >> 16) & 1);
    return (u16)(r >> 16);
}

// ---------------- Kernel 0: Wt[f][k] bf16 = transpose(W [k][f] fp32) ----------------
// Also zeroes fs/fd for k_proj's atomic accumulation (32 blk x 256 thr = 8192 = 2*NN).
__global__ __launch_bounds__(256) void k_wt(const float* __restrict__ W,
                                            u16* __restrict__ Wt,
                                            float* __restrict__ fs,
                                            float* __restrict__ fd) {
    __shared__ float s[64 * 65];
    const int t  = threadIdx.x;
    const int g  = (blockIdx.y * gridDim.x + blockIdx.x) * 256 + t;
    if (g < NN) fs[g] = 0.f; else fd[g - NN] = 0.f;
    const int f0 = blockIdx.x * 64;
    const int k0 = blockIdx.y * 64;
    #pragma unroll
    for (int p = 0; p < 4; ++p) {
        int q = t + 256 * p, rr = q >> 4, cc = q & 15;
        float4 w4 = *(const float4*)&W[(size_t)(k0 + rr) * FOUT + f0 + cc * 4];
        s[(cc * 4 + 0) * 65 + rr] = w4.x;
        s[(cc * 4 + 1) * 65 + rr] = w4.y;
        s[(cc * 4 + 2) * 65 + rr] = w4.z;
        s[(cc * 4 + 3) * 65 + rr] = w4.w;
    }
    __syncthreads();
    #pragma unroll
    for (int p = 0; p < 4; ++p) {
        int q = t + 256 * p, f = q >> 4, kg = q & 15;
        ushort4 o;
        o.x = f2bf(s[f * 65 + kg * 4 + 0]);
        o.y = f2bf(s[f * 65 + kg * 4 + 1]);
        o.z = f2bf(s[f * 65 + kg * 4 + 2]);
        o.w = f2bf(s[f * 65 + kg * 4 + 3]);
        *(ushort4*)&Wt[(size_t)(f0 + f) * FIN + k0 + kg * 4] = o;
    }
}

// ------- Kernel 1: proj -> whT bf16 tiles + f_src/f_dst partials + adj->bits pack -------
// The 64 MB adj stream is fused here (overlaps MFMA/staging); each block packs the 8
// rows [i0 + bx*8, +8), so every adj row is packed exactly once chip-wide.
#define HS 520   // u16 LDS row stride (1040 B = 65*16, aligned)
__global__ __launch_bounds__(256) void k_proj(const float* __restrict__ h,
                                              const u16* __restrict__ Wt,
                                              const float* __restrict__ bias,
                                              const float* __restrict__ a1,
                                              const float* __restrict__ a2,
                                              const int* __restrict__ adj,
                                              u16* __restrict__ whT,
                                              float* __restrict__ fs,
                                              float* __restrict__ fd,
                                              u64* __restrict__ bits) {
    __shared__ u16 s_h[32 * HS];   // 32 rows x 512 k bf16
    const int t  = threadIdx.x;
    const int f0 = blockIdx.x * 64;
    const int i0 = blockIdx.y * 32;
    #pragma unroll
    for (int p = 0; p < 16; ++p) {
        int q = t + 256 * p, row = q >> 7, c4 = q & 127;
        float4 v = *(const float4*)&h[(size_t)(i0 + row) * FIN + c4 * 4];
        ushort4 o; o.x = f2bf(v.x); o.y = f2bf(v.y); o.z = f2bf(v.z); o.w = f2bf(v.w);
        *(ushort4*)&s_h[row * HS + c4 * 4] = o;
    }
    __syncthreads();
    const int w = t >> 6, l = t & 63, n = l & 15, quad = l >> 4;
    const int hh = w & 1, fh = w >> 1;
    f32x4 acc[2] = {{0.f,0.f,0.f,0.f},{0.f,0.f,0.f,0.f}};
    #pragma unroll
    for (int k0 = 0; k0 < FIN; k0 += 32) {
        short8 a = *(const short8*)&s_h[(hh * 16 + n) * HS + k0 + quad * 8];
        short8 b0 = *(const short8*)&Wt[(size_t)(f0 + fh * 32 + n) * FIN + k0 + quad * 8];
        short8 b1 = *(const short8*)&Wt[(size_t)(f0 + fh * 32 + 16 + n) * FIN + k0 + quad * 8];
        acc[0] = __builtin_amdgcn_mfma_f32_16x16x32_bf16(a, b0, acc[0], 0, 0, 0);
        acc[1] = __builtin_amdgcn_mfma_f32_16x16x32_bf16(a, b1, acc[1], 0, 0, 0);
    }
    const int fb = f0 + fh * 32 + n;
    const float bv0 = bias[fb],  bv1 = bias[fb + 16];
    const float a10 = a1[fb],    a11 = a1[fb + 16];
    const float a20 = a2[fb],    a21 = a2[fb + 16];
    u16* wt_tile = whT + (size_t)(i0 >> 5) * (FOUT * 32);
    float d1[4], d2[4];
    #pragma unroll
    for (int r = 0; r < 4; ++r) {
        const int ic = hh * 16 + quad * 4 + r;       // i - i0
        const float v0 = acc[0][r] + bv0;
        const float v1 = acc[1][r] + bv1;
        wt_tile[fb * 32 + ic]        = f2bf(v0);
        wt_tile[(fb + 16) * 32 + ic] = f2bf(v1);
        d1[r] = v0 * a10 + v1 * a11;
        d2[r] = v0 * a20 + v1 * a21;
    }
    #pragma unroll
    for (int m = 1; m < 16; m <<= 1) {
        #pragma unroll
        for (int r = 0; r < 4; ++r) {
            d1[r] += __shfl_xor(d1[r], m);
            d2[r] += __shfl_xor(d2[r], m);
        }
    }
    if (n == 0) {
        #pragma unroll
        for (int r = 0; r < 4; ++r) {
            const int i = i0 + hh * 16 + quad * 4 + r;
            atomicAdd(&fs[i], d1[r]);
            atomicAdd(&fd[i], d2[r]);
        }
    }
    // ---- adj -> bitmask tail: wave w packs rows i0 + bx*8 + 2w, +1 ----
    {
        const int rr = i0 + (blockIdx.x << 3) + (w << 1);
        #pragma unroll
        for (int s = 0; s < 2; ++s) {
            const size_t ab = (size_t)(rr + s) * NN;
            u64* dst = bits + (size_t)(rr + s) * 64;
            #pragma unroll 2
            for (int o = 0; o < 16; ++o) {
                u64 q0 = __ballot(adj[ab + (o * 4 + 0) * 64 + l] > 0);
                u64 q1 = __ballot(adj[ab + (o * 4 + 1) * 64 + l] > 0);
                u64 q2 = __ballot(adj[ab + (o * 4 + 2) * 64 + l] > 0);
                u64 q3 = __ballot(adj[ab + (o * 4 + 3) * 64 + l] > 0);
                if (l == 0) {
                    dst[o * 4 + 0] = q0;
                    dst[o * 4 + 1] = q1;
                    dst[o * 4 + 2] = q2;
                    dst[o * 4 + 3] = q3;
                }
            }
        }
    }
}

// ------ Kernel 2: barrier-free fused mask+softmax-num + MFMA P@wh ------
// exp(leaky(fs_i+fd_j)) = max(E_i*F_j, G_i*H_j). F/H computed per-block into a 4 KB
// LDS table (one startup barrier only). b-frags double-buffered in NAMED registers,
// issued one K-step ahead (load->use distance ~370 cy covers L2). P->bf16 via
// v_cvt_pk_bf16_f32 (halves the packing VALU). No loop barriers, no LDS P tile.
#define BI 32
#define CJ 8    // j-chunks; must equal gridDim.y of k_attn

__device__ __forceinline__ void comp_step(
        const short8& b0, const short8& b1, const short8& b2, const short8& b3,
        const float* s_F, const float* s_H, int joff, int jq8,
        u32 w0, u32 w1, float E0, float G0, float E1, float G1,
        f32x4 (&acc)[2][4], float& rs0, float& rs1) {
    const float4 Fa = *(const float4*)&s_F[joff + jq8];
    const float4 Fb = *(const float4*)&s_F[joff + jq8 + 4];
    const float4 Ha = *(const float4*)&s_H[joff + jq8];
    const float4 Hb = *(const float4*)&s_H[joff + jq8 + 4];
    const u32 bw0 = w0 >> jq8, bw1 = w1 >> jq8;
    float q0, q1, q2, q3, q4, q5, q6, q7;
    u32 d0, d1, d2, d3;
    union { short8 v; u32 d[4]; } o0, o1;
#define PEL1(FV, HV, BW, K, E, G, RS, PP) do { \
        float _m = fmaxf((E) * (FV), (G) * (HV)); \
        PP = ((BW) & (1u << (K))) ? _m : 0.f; RS += PP; } while (0)
    PEL1(Fa.x, Ha.x, bw0, 0, E0, G0, rs0, q0);
    PEL1(Fa.y, Ha.y, bw0, 1, E0, G0, rs0, q1);
    PEL1(Fa.z, Ha.z, bw0, 2, E0, G0, rs0, q2);
    PEL1(Fa.w, Ha.w, bw0, 3, E0, G0, rs0, q3);
    PEL1(Fb.x, Hb.x, bw0, 4, E0, G0, rs0, q4);
    PEL1(Fb.y, Hb.y, bw0, 5, E0, G0, rs0, q5);
    PEL1(Fb.z, Hb.z, bw0, 6, E0, G0, rs0, q6);
    PEL1(Fb.w, Hb.w, bw0, 7, E0, G0, rs0, q7);
    asm("v_cvt_pk_bf16_f32 %0, %1, %2" : "=v"(d0) : "v"(q0), "v"(q1));
    asm("v_cvt_pk_bf16_f32 %0, %1, %2" : "=v"(d1) : "v"(q2), "v"(q3));
    asm("v_cvt_pk_bf16_f32 %0, %1, %2" : "=v"(d2) : "v"(q4), "v"(q5));
    asm("v_cvt_pk_bf16_f32 %0, %1, %2" : "=v"(d3) : "v"(q6), "v"(q7));
    o0.d[0] = d0; o0.d[1] = d1; o0.d[2] = d2; o0.d[3] = d3;
    PEL1(Fa.x, Ha.x, bw1, 0, E1, G1, rs1, q0);
    PEL1(Fa.y, Ha.y, bw1, 1, E1, G1, rs1, q1);
    PEL1(Fa.z, Ha.z, bw1, 2, E1, G1, rs1, q2);
    PEL1(Fa.w, Ha.w, bw1, 3, E1, G1, rs1, q3);
    PEL1(Fb.x, Hb.x, bw1, 4, E1, G1, rs1, q4);
    PEL1(Fb.y, Hb.y, bw1, 5, E1, G1, rs1, q5);
    PEL1(Fb.z, Hb.z, bw1, 6, E1, G1, rs1, q6);
    PEL1(Fb.w, Hb.w, bw1, 7, E1, G1, rs1, q7);
#undef PEL1
    asm("v_cvt_pk_bf16_f32 %0, %1, %2" : "=v"(d0) : "v"(q0), "v"(q1));
    asm("v_cvt_pk_bf16_f32 %0, %1, %2" : "=v"(d1) : "v"(q2), "v"(q3));
    asm("v_cvt_pk_bf16_f32 %0, %1, %2" : "=v"(d2) : "v"(q4), "v"(q5));
    asm("v_cvt_pk_bf16_f32 %0, %1, %2" : "=v"(d3) : "v"(q6), "v"(q7));
    o1.d[0] = d0; o1.d[1] = d1; o1.d[2] = d2; o1.d[3] = d3;
    __builtin_amdgcn_s_setprio(1);
    acc[0][0] = __builtin_amdgcn_mfma_f32_16x16x32_bf16(o0.v, b0, acc[0][0], 0, 0, 0);
    acc[0][1] = __builtin_amdgcn_mfma_f32_16x16x32_bf16(o0.v, b1, acc[0][1], 0, 0, 0);
    acc[0][2] = __builtin_amdgcn_mfma_f32_16x16x32_bf16(o0.v, b2, acc[0][2], 0, 0, 0);
    acc[0][3] = __builtin_amdgcn_mfma_f32_16x16x32_bf16(o0.v, b3, acc[0][3], 0, 0, 0);
    acc[1][0] = __builtin_amdgcn_mfma_f32_16x16x32_bf16(o1.v, b0, acc[1][0], 0, 0, 0);
    acc[1][1] = __builtin_amdgcn_mfma_f32_16x16x32_bf16(o1.v, b1, acc[1][1], 0, 0, 0);
    acc[1][2] = __builtin_amdgcn_mfma_f32_16x16x32_bf16(o1.v, b2, acc[1][2], 0, 0, 0);
    acc[1][3] = __builtin_amdgcn_mfma_f32_16x16x32_bf16(o1.v, b3, acc[1][3], 0, 0, 0);
    __builtin_amdgcn_s_setprio(0);
}

__global__ __launch_bounds__(256) void k_attn(const u32* __restrict__ bits,
                                              const u16* __restrict__ whT,
                                              const float* __restrict__ fs,
                                              const float* __restrict__ fd,
                                              const float* __restrict__ ab,
                                              float* __restrict__ part,
                                              float* __restrict__ psum) {
    __shared__ float s_F[NN / CJ], s_H[NN / CJ];   // 2 x 2 KB
    const int t = threadIdx.x;
    const int w = t >> 6, l = t & 63, n = l & 15, quad = l >> 4;
    const int i0 = blockIdx.x * BI;
    const int c  = blockIdx.y;
    const int jbeg = c * (NN / CJ), jend = jbeg + (NN / CJ);
    const int fw  = w * 64;
    const int jq8 = quad * 8;

    const float abv = ab[0];
    const float s0 = fs[i0 + n] + abv;
    const float s1 = fs[i0 + 16 + n] + abv;
    const float E0 = __expf(s0), G0 = __expf(ALPHA * s0);
    const float E1 = __expf(s1), G1 = __expf(ALPHA * s1);

    const u32* B0 = bits + (size_t)(i0 + n) * 128;
    const u32* B1 = bits + (size_t)(i0 + 16 + n) * 128;
    uint4 m0 = *(const uint4*)&B0[jbeg >> 5];
    uint4 m1 = *(const uint4*)&B1[jbeg >> 5];

    short8 Ab0, Ab1, Ab2, Ab3, Bb0, Bb1, Bb2, Bb3;
#define LDB(P, J0) do { const u16* tb_ = whT + (size_t)((J0) >> 5) * (FOUT * 32) + quad * 8; \
        P##0 = *(const short8*)&tb_[(fw + n) * 32]; \
        P##1 = *(const short8*)&tb_[(fw + n + 16) * 32]; \
        P##2 = *(const short8*)&tb_[(fw + n + 32) * 32]; \
        P##3 = *(const short8*)&tb_[(fw + n + 48) * 32]; } while (0)

    LDB(Ab, jbeg);   // prologue load, overlaps F/H fill + barrier

    // F/H table for this block's j-chunk (512 j): threads 0..127, 4 j each
    if (t < 128) {
        float4 v = *(const float4*)&fd[jbeg + t * 4];
        float4 F, H;
        F.x = __expf(v.x); F.y = __expf(v.y); F.z = __expf(v.z); F.w = __expf(v.w);
        H.x = __expf(ALPHA * v.x); H.y = __expf(ALPHA * v.y);
        H.z = __expf(ALPHA * v.z); H.w = __expf(ALPHA * v.w);
        *(float4*)&s_F[t * 4] = F;
        *(float4*)&s_H[t * 4] = H;
    }
    __syncthreads();   // only barrier in the kernel

    f32x4 acc[2][4] = {{{0.f,0.f,0.f,0.f},{0.f,0.f,0.f,0.f},{0.f,0.f,0.f,0.f},{0.f,0.f,0.f,0.f}},
                       {{0.f,0.f,0.f,0.f},{0.f,0.f,0.f,0.f},{0.f,0.f,0.f,0.f},{0.f,0.f,0.f,0.f}}};
    float rs0 = 0.f, rs1 = 0.f;

    #pragma unroll 1
    for (int jb = jbeg; jb < jend; jb += 128) {
        const uint4 cm0 = m0, cm1 = m1;
        if (jb + 128 < jend) {
            m0 = *(const uint4*)&B0[(jb + 128) >> 5];
            m1 = *(const uint4*)&B1[(jb + 128) >> 5];
        }
        LDB(Bb, jb + 32);
        comp_step(Ab0, Ab1, Ab2, Ab3, s_F, s_H, jb - jbeg,      jq8, cm0.x, cm1.x, E0, G0, E1, G1, acc, rs0, rs1);
        LDB(Ab, jb + 64);
        comp_step(Bb0, Bb1, Bb2, Bb3, s_F, s_H, jb - jbeg + 32, jq8, cm0.y, cm1.y, E0, G0, E1, G1, acc, rs0, rs1);
        LDB(Bb, jb + 96);
        comp_step(Ab0, Ab1, Ab2, Ab3, s_F, s_H, jb - jbeg + 64, jq8, cm0.z, cm1.z, E0, G0, E1, G1, acc, rs0, rs1);
        if (jb + 128 < jend) LDB(Ab, jb + 128);
        comp_step(Bb0, Bb1, Bb2, Bb3, s_F, s_H, jb - jbeg + 96, jq8, cm0.w, cm1.w, E0, G0, E1, G1, acc, rs0, rs1);
    }
#undef LDB
    // ---- denominators: sum over quads (lane bits 4,5); all 4 waves identical, w0 writes ----
    rs0 += __shfl_xor(rs0, 16); rs0 += __shfl_xor(rs0, 32);
    rs1 += __shfl_xor(rs1, 16); rs1 += __shfl_xor(rs1, 32);
    if (w == 0 && quad == 0) {
        psum[(size_t)c * NN + i0 + n]      = rs0;
        psum[(size_t)c * NN + i0 + 16 + n] = rs1;
    }
    // ---- partial numerators ----
    float* pc = part + ((size_t)c * NN + i0) * FOUT;
    #pragma unroll
    for (int hf = 0; hf < 2; ++hf)
        #pragma unroll
        for (int u = 0; u < 4; ++u)
            #pragma unroll
            for (int r = 0; r < 4; ++r)
                pc[(size_t)(hf * 16 + quad * 4 + r) * FOUT + fw + u * 16 + n] = acc[hf][u][r];
}

// ------ Kernel 3: combine partials, normalize, elu ------
__global__ __launch_bounds__(256) void k_fin(const float* __restrict__ part,
                                             const float* __restrict__ psum,
                                             float* __restrict__ out, int C) {
    const int g = blockIdx.x * 256 + threadIdx.x;
    const int i = g >> 6;
    const size_t s4 = (size_t)NN * FOUT / 4;
    float4 a = ((const float4*)part)[g];
    float s = psum[i];
    for (int c = 1; c < C; ++c) {
        float4 bb = ((const float4*)part)[g + (size_t)c * s4];
        a.x += bb.x; a.y += bb.y; a.z += bb.z; a.w += bb.w;
        s += psum[(size_t)c * NN + i];
    }
    const float inv = 1.0f / s;
    a.x *= inv; a.y *= inv; a.z *= inv; a.w *= inv;
    a.x = a.x > 0.f ? a.x : __expf(a.x) - 1.f;
    a.y = a.y > 0.f ? a.y : __expf(a.y) - 1.f;
    a.z = a.z > 0.f ? a.z : __expf(a.z) - 1.f;
    a.w = a.w > 0.f ? a.w : __expf(a.w) - 1.f;
    ((float4*)out)[g] = a;
}

extern "C" void kernel_launch(void* const* d_in, const int* in_sizes, int n_in,
                              void* d_out, int out_size, void* d_ws, size_t ws_size,
                              hipStream_t stream) {
    const int*   adj = (const int*)  d_in[0];
    const float* h   = (const float*)d_in[1];
    const float* W   = (const float*)d_in[2];
    const float* b   = (const float*)d_in[3];
    const float* a1  = (const float*)d_in[4];
    const float* a2  = (const float*)d_in[5];
    const float* ab  = (const float*)d_in[6];
    float* out = (float*)d_out;

    const int C = CJ;

    float* fs   = (float*)d_ws;
    float* fd   = fs + NN;
    float* psum = fd + NN;
    float* part = psum + (size_t)C * NN;
    u16*   Wt   = (u16*)(part + (size_t)C * NN * FOUT);
    u16*   whT  = Wt + (size_t)FOUT * FIN;
    u64*   bits = (u64*)(whT + (size_t)NN * FOUT);

    k_wt  <<<dim3(FOUT / 64, FIN / 64), 256, 0, stream>>>(W, Wt, fs, fd);
    k_proj<<<dim3(FOUT / 64, NN / 32), 256, 0, stream>>>(h, Wt, b, a1, a2, adj, whT, fs, fd, bits);
    k_attn<<<dim3(NN / BI, CJ), 256, 0, stream>>>((const u32*)bits, whT, fs, fd, ab, part, psum);
    k_fin <<<(NN * FOUT / 4) / 256, 256, 0, stream>>>(part, psum, out, C);
}

// Round 8
// 154.438 us; speedup vs baseline: 1.1445x; 1.0868x over previous
//
#include <hip/hip_runtime.h>

#define NN   4096
#define FIN  512
#define FOUT 256
#define ALPHA 0.2f

typedef __attribute__((ext_vector_type(8))) short short8;
typedef __attribute__((ext_vector_type(4))) float f32x4;
typedef unsigned short u16;
typedef unsigned int u32;
typedef unsigned long long u64;

__device__ __forceinline__ u16 f2bf(float x) {   // round-to-nearest-even
    union { float f; unsigned u; } v; v.f = x;
    unsigned r = v.u + 0x7FFF + ((v.u >> 16) & 1);
    return (u16)(r >> 16);
}

// ---------------- Kernel 0: Wt[f][k] bf16 = transpose(W [k][f] fp32) ----------------
// Also zeroes fs/fd for k_pb's atomic accumulation (32 blk x 256 thr = 8192 = 2*NN).
__global__ __launch_bounds__(256) void k_wt(const float* __restrict__ W,
                                            u16* __restrict__ Wt,
                                            float* __restrict__ fs,
                                            float* __restrict__ fd) {
    __shared__ float s[64 * 65];
    const int t  = threadIdx.x;
    const int g  = (blockIdx.y * gridDim.x + blockIdx.x) * 256 + t;
    if (g < NN) fs[g] = 0.f; else fd[g - NN] = 0.f;
    const int f0 = blockIdx.x * 64;
    const int k0 = blockIdx.y * 64;
    #pragma unroll
    for (int p = 0; p < 4; ++p) {
        int q = t + 256 * p, rr = q >> 4, cc = q & 15;
        float4 w4 = *(const float4*)&W[(size_t)(k0 + rr) * FOUT + f0 + cc * 4];
        s[(cc * 4 + 0) * 65 + rr] = w4.x;
        s[(cc * 4 + 1) * 65 + rr] = w4.y;
        s[(cc * 4 + 2) * 65 + rr] = w4.z;
        s[(cc * 4 + 3) * 65 + rr] = w4.w;
    }
    __syncthreads();
    #pragma unroll
    for (int p = 0; p < 4; ++p) {
        int q = t + 256 * p, f = q >> 4, kg = q & 15;
        ushort4 o;
        o.x = f2bf(s[f * 65 + kg * 4 + 0]);
        o.y = f2bf(s[f * 65 + kg * 4 + 1]);
        o.z = f2bf(s[f * 65 + kg * 4 + 2]);
        o.w = f2bf(s[f * 65 + kg * 4 + 3]);
        *(ushort4*)&Wt[(size_t)(f0 + f) * FIN + k0 + kg * 4] = o;
    }
}

// ------- Kernel 1 (grid-fused): blocks 0-511 = proj, blocks 512-2559 = adj->bits -------
// proj: whT bf16 tiles + f_src/f_dst partials (R5's proven body).
// bits: BW-tuned pack — 2 rows/block, half-row/wave, 8 fully-unrolled iters
//       (32 independent coalesced loads in flight/wave), 8192 waves chip-wide.
// The two populations co-reside: bits blocks use the VMEM pipe while proj blocks
// use MFMA/LDS -> the 64 MB adj stream hides under proj's compute.
#define HS 520   // u16 LDS row stride (1040 B = 65*16, aligned)
__global__ __launch_bounds__(256) void k_pb(const float* __restrict__ h,
                                            const u16* __restrict__ Wt,
                                            const float* __restrict__ bias,
                                            const float* __restrict__ a1,
                                            const float* __restrict__ a2,
                                            const int* __restrict__ adj,
                                            u16* __restrict__ whT,
                                            float* __restrict__ fs,
                                            float* __restrict__ fd,
                                            u64* __restrict__ bits) {
    __shared__ u16 s_h[32 * HS];   // 32 rows x 512 k bf16 (proj path only)
    const int bid = blockIdx.x;
    const int t   = threadIdx.x;
    if (bid >= 512) {
        // ---------------- bits path ----------------
        const int l = t & 63, wv = t >> 6;
        const int row  = (bid - 512) * 2 + (wv >> 1);
        const int half = wv & 1;
        const size_t base = (size_t)row * NN + half * 2048;
        u64* dst = bits + (size_t)row * 64 + half * 32;
        #pragma unroll
        for (int o = 0; o < 8; ++o) {
            u64 b0 = __ballot(adj[base + (o * 4 + 0) * 64 + l] > 0);
            u64 b1 = __ballot(adj[base + (o * 4 + 1) * 64 + l] > 0);
            u64 b2 = __ballot(adj[base + (o * 4 + 2) * 64 + l] > 0);
            u64 b3 = __ballot(adj[base + (o * 4 + 3) * 64 + l] > 0);
            if (l == 0) {
                dst[o * 4 + 0] = b0;
                dst[o * 4 + 1] = b1;
                dst[o * 4 + 2] = b2;
                dst[o * 4 + 3] = b3;
            }
        }
        return;
    }
    // ---------------- proj path ----------------
    const int f0 = (bid & 3) * 64;
    const int i0 = (bid >> 2) * 32;
    #pragma unroll
    for (int p = 0; p < 16; ++p) {
        int q = t + 256 * p, row = q >> 7, c4 = q & 127;
        float4 v = *(const float4*)&h[(size_t)(i0 + row) * FIN + c4 * 4];
        ushort4 o; o.x = f2bf(v.x); o.y = f2bf(v.y); o.z = f2bf(v.z); o.w = f2bf(v.w);
        *(ushort4*)&s_h[row * HS + c4 * 4] = o;
    }
    __syncthreads();
    const int w = t >> 6, l = t & 63, n = l & 15, quad = l >> 4;
    const int hh = w & 1, fh = w >> 1;
    f32x4 acc[2] = {{0.f,0.f,0.f,0.f},{0.f,0.f,0.f,0.f}};
    #pragma unroll
    for (int k0 = 0; k0 < FIN; k0 += 32) {
        short8 a = *(const short8*)&s_h[(hh * 16 + n) * HS + k0 + quad * 8];
        short8 b0 = *(const short8*)&Wt[(size_t)(f0 + fh * 32 + n) * FIN + k0 + quad * 8];
        short8 b1 = *(const short8*)&Wt[(size_t)(f0 + fh * 32 + 16 + n) * FIN + k0 + quad * 8];
        acc[0] = __builtin_amdgcn_mfma_f32_16x16x32_bf16(a, b0, acc[0], 0, 0, 0);
        acc[1] = __builtin_amdgcn_mfma_f32_16x16x32_bf16(a, b1, acc[1], 0, 0, 0);
    }
    const int fb = f0 + fh * 32 + n;
    const float bv0 = bias[fb],  bv1 = bias[fb + 16];
    const float a10 = a1[fb],    a11 = a1[fb + 16];
    const float a20 = a2[fb],    a21 = a2[fb + 16];
    u16* wt_tile = whT + (size_t)(i0 >> 5) * (FOUT * 32);
    float d1[4], d2[4];
    #pragma unroll
    for (int r = 0; r < 4; ++r) {
        const int ic = hh * 16 + quad * 4 + r;       // i - i0
        const float v0 = acc[0][r] + bv0;
        const float v1 = acc[1][r] + bv1;
        wt_tile[fb * 32 + ic]        = f2bf(v0);
        wt_tile[(fb + 16) * 32 + ic] = f2bf(v1);
        d1[r] = v0 * a10 + v1 * a11;
        d2[r] = v0 * a20 + v1 * a21;
    }
    #pragma unroll
    for (int m = 1; m < 16; m <<= 1) {
        #pragma unroll
        for (int r = 0; r < 4; ++r) {
            d1[r] += __shfl_xor(d1[r], m);
            d2[r] += __shfl_xor(d2[r], m);
        }
    }
    if (n == 0) {
        #pragma unroll
        for (int r = 0; r < 4; ++r) {
            const int i = i0 + hh * 16 + quad * 4 + r;
            atomicAdd(&fs[i], d1[r]);
            atomicAdd(&fd[i], d2[r]);
        }
    }
}

// ------ Kernel 2: barrier-free fused mask+softmax-num + MFMA P@wh (unchanged R7) ------
// exp(leaky(fs_i+fd_j)) = max(E_i*F_j, G_i*H_j). F/H computed per-block into a 4 KB
// LDS table (one startup barrier only). b-frags double-buffered in NAMED registers,
// issued one K-step ahead. P->bf16 via v_cvt_pk_bf16_f32. No loop barriers.
#define BI 32
#define CJ 8    // j-chunks; must equal gridDim.y of k_attn

__device__ __forceinline__ void comp_step(
        const short8& b0, const short8& b1, const short8& b2, const short8& b3,
        const float* s_F, const float* s_H, int joff, int jq8,
        u32 w0, u32 w1, float E0, float G0, float E1, float G1,
        f32x4 (&acc)[2][4], float& rs0, float& rs1) {
    const float4 Fa = *(const float4*)&s_F[joff + jq8];
    const float4 Fb = *(const float4*)&s_F[joff + jq8 + 4];
    const float4 Ha = *(const float4*)&s_H[joff + jq8];
    const float4 Hb = *(const float4*)&s_H[joff + jq8 + 4];
    const u32 bw0 = w0 >> jq8, bw1 = w1 >> jq8;
    float q0, q1, q2, q3, q4, q5, q6, q7;
    u32 d0, d1, d2, d3;
    union { short8 v; u32 d[4]; } o0, o1;
#define PEL1(FV, HV, BW, K, E, G, RS, PP) do { \
        float _m = fmaxf((E) * (FV), (G) * (HV)); \
        PP = ((BW) & (1u << (K))) ? _m : 0.f; RS += PP; } while (0)
    PEL1(Fa.x, Ha.x, bw0, 0, E0, G0, rs0, q0);
    PEL1(Fa.y, Ha.y, bw0, 1, E0, G0, rs0, q1);
    PEL1(Fa.z, Ha.z, bw0, 2, E0, G0, rs0, q2);
    PEL1(Fa.w, Ha.w, bw0, 3, E0, G0, rs0, q3);
    PEL1(Fb.x, Hb.x, bw0, 4, E0, G0, rs0, q4);
    PEL1(Fb.y, Hb.y, bw0, 5, E0, G0, rs0, q5);
    PEL1(Fb.z, Hb.z, bw0, 6, E0, G0, rs0, q6);
    PEL1(Fb.w, Hb.w, bw0, 7, E0, G0, rs0, q7);
    asm("v_cvt_pk_bf16_f32 %0, %1, %2" : "=v"(d0) : "v"(q0), "v"(q1));
    asm("v_cvt_pk_bf16_f32 %0, %1, %2" : "=v"(d1) : "v"(q2), "v"(q3));
    asm("v_cvt_pk_bf16_f32 %0, %1, %2" : "=v"(d2) : "v"(q4), "v"(q5));
    asm("v_cvt_pk_bf16_f32 %0, %1, %2" : "=v"(d3) : "v"(q6), "v"(q7));
    o0.d[0] = d0; o0.d[1] = d1; o0.d[2] = d2; o0.d[3] = d3;
    PEL1(Fa.x, Ha.x, bw1, 0, E1, G1, rs1, q0);
    PEL1(Fa.y, Ha.y, bw1, 1, E1, G1, rs1, q1);
    PEL1(Fa.z, Ha.z, bw1, 2, E1, G1, rs1, q2);
    PEL1(Fa.w, Ha.w, bw1, 3, E1, G1, rs1, q3);
    PEL1(Fb.x, Hb.x, bw1, 4, E1, G1, rs1, q4);
    PEL1(Fb.y, Hb.y, bw1, 5, E1, G1, rs1, q5);
    PEL1(Fb.z, Hb.z, bw1, 6, E1, G1, rs1, q6);
    PEL1(Fb.w, Hb.w, bw1, 7, E1, G1, rs1, q7);
#undef PEL1
    asm("v_cvt_pk_bf16_f32 %0, %1, %2" : "=v"(d0) : "v"(q0), "v"(q1));
    asm("v_cvt_pk_bf16_f32 %0, %1, %2" : "=v"(d1) : "v"(q2), "v"(q3));
    asm("v_cvt_pk_bf16_f32 %0, %1, %2" : "=v"(d2) : "v"(q4), "v"(q5));
    asm("v_cvt_pk_bf16_f32 %0, %1, %2" : "=v"(d3) : "v"(q6), "v"(q7));
    o1.d[0] = d0; o1.d[1] = d1; o1.d[2] = d2; o1.d[3] = d3;
    __builtin_amdgcn_s_setprio(1);
    acc[0][0] = __builtin_amdgcn_mfma_f32_16x16x32_bf16(o0.v, b0, acc[0][0], 0, 0, 0);
    acc[0][1] = __builtin_amdgcn_mfma_f32_16x16x32_bf16(o0.v, b1, acc[0][1], 0, 0, 0);
    acc[0][2] = __builtin_amdgcn_mfma_f32_16x16x32_bf16(o0.v, b2, acc[0][2], 0, 0, 0);
    acc[0][3] = __builtin_amdgcn_mfma_f32_16x16x32_bf16(o0.v, b3, acc[0][3], 0, 0, 0);
    acc[1][0] = __builtin_amdgcn_mfma_f32_16x16x32_bf16(o1.v, b0, acc[1][0], 0, 0, 0);
    acc[1][1] = __builtin_amdgcn_mfma_f32_16x16x32_bf16(o1.v, b1, acc[1][1], 0, 0, 0);
    acc[1][2] = __builtin_amdgcn_mfma_f32_16x16x32_bf16(o1.v, b2, acc[1][2], 0, 0, 0);
    acc[1][3] = __builtin_amdgcn_mfma_f32_16x16x32_bf16(o1.v, b3, acc[1][3], 0, 0, 0);
    __builtin_amdgcn_s_setprio(0);
}

__global__ __launch_bounds__(256) void k_attn(const u32* __restrict__ bits,
                                              const u16* __restrict__ whT,
                                              const float* __restrict__ fs,
                                              const float* __restrict__ fd,
                                              const float* __restrict__ ab,
                                              float* __restrict__ part,
                                              float* __restrict__ psum) {
    __shared__ float s_F[NN / CJ], s_H[NN / CJ];   // 2 x 2 KB
    const int t = threadIdx.x;
    const int w = t >> 6, l = t & 63, n = l & 15, quad = l >> 4;
    const int i0 = blockIdx.x * BI;
    const int c  = blockIdx.y;
    const int jbeg = c * (NN / CJ), jend = jbeg + (NN / CJ);
    const int fw  = w * 64;
    const int jq8 = quad * 8;

    const float abv = ab[0];
    const float s0 = fs[i0 + n] + abv;
    const float s1 = fs[i0 + 16 + n] + abv;
    const float E0 = __expf(s0), G0 = __expf(ALPHA * s0);
    const float E1 = __expf(s1), G1 = __expf(ALPHA * s1);

    const u32* B0 = bits + (size_t)(i0 + n) * 128;
    const u32* B1 = bits + (size_t)(i0 + 16 + n) * 128;
    uint4 m0 = *(const uint4*)&B0[jbeg >> 5];
    uint4 m1 = *(const uint4*)&B1[jbeg >> 5];

    short8 Ab0, Ab1, Ab2, Ab3, Bb0, Bb1, Bb2, Bb3;
#define LDB(P, J0) do { const u16* tb_ = whT + (size_t)((J0) >> 5) * (FOUT * 32) + quad * 8; \
        P##0 = *(const short8*)&tb_[(fw + n) * 32]; \
        P##1 = *(const short8*)&tb_[(fw + n + 16) * 32]; \
        P##2 = *(const short8*)&tb_[(fw + n + 32) * 32]; \
        P##3 = *(const short8*)&tb_[(fw + n + 48) * 32]; } while (0)

    LDB(Ab, jbeg);   // prologue load, overlaps F/H fill + barrier

    // F/H table for this block's j-chunk (512 j): threads 0..127, 4 j each
    if (t < 128) {
        float4 v = *(const float4*)&fd[jbeg + t * 4];
        float4 F, H;
        F.x = __expf(v.x); F.y = __expf(v.y); F.z = __expf(v.z); F.w = __expf(v.w);
        H.x = __expf(ALPHA * v.x); H.y = __expf(ALPHA * v.y);
        H.z = __expf(ALPHA * v.z); H.w = __expf(ALPHA * v.w);
        *(float4*)&s_F[t * 4] = F;
        *(float4*)&s_H[t * 4] = H;
    }
    __syncthreads();   // only barrier in the kernel

    f32x4 acc[2][4] = {{{0.f,0.f,0.f,0.f},{0.f,0.f,0.f,0.f},{0.f,0.f,0.f,0.f},{0.f,0.f,0.f,0.f}},
                       {{0.f,0.f,0.f,0.f},{0.f,0.f,0.f,0.f},{0.f,0.f,0.f,0.f},{0.f,0.f,0.f,0.f}}};
    float rs0 = 0.f, rs1 = 0.f;

    #pragma unroll 1
    for (int jb = jbeg; jb < jend; jb += 128) {
        const uint4 cm0 = m0, cm1 = m1;
        if (jb + 128 < jend) {
            m0 = *(const uint4*)&B0[(jb + 128) >> 5];
            m1 = *(const uint4*)&B1[(jb + 128) >> 5];
        }
        LDB(Bb, jb + 32);
        comp_step(Ab0, Ab1, Ab2, Ab3, s_F, s_H, jb - jbeg,      jq8, cm0.x, cm1.x, E0, G0, E1, G1, acc, rs0, rs1);
        LDB(Ab, jb + 64);
        comp_step(Bb0, Bb1, Bb2, Bb3, s_F, s_H, jb - jbeg + 32, jq8, cm0.y, cm1.y, E0, G0, E1, G1, acc, rs0, rs1);
        LDB(Bb, jb + 96);
        comp_step(Ab0, Ab1, Ab2, Ab3, s_F, s_H, jb - jbeg + 64, jq8, cm0.z, cm1.z, E0, G0, E1, G1, acc, rs0, rs1);
        if (jb + 128 < jend) LDB(Ab, jb + 128);
        comp_step(Bb0, Bb1, Bb2, Bb3, s_F, s_H, jb - jbeg + 96, jq8, cm0.w, cm1.w, E0, G0, E1, G1, acc, rs0, rs1);
    }
#undef LDB
    // ---- denominators: sum over quads (lane bits 4,5); all 4 waves identical, w0 writes ----
    rs0 += __shfl_xor(rs0, 16); rs0 += __shfl_xor(rs0, 32);
    rs1 += __shfl_xor(rs1, 16); rs1 += __shfl_xor(rs1, 32);
    if (w == 0 && quad == 0) {
        psum[(size_t)c * NN + i0 + n]      = rs0;
        psum[(size_t)c * NN + i0 + 16 + n] = rs1;
    }
    // ---- partial numerators ----
    float* pc = part + ((size_t)c * NN + i0) * FOUT;
    #pragma unroll
    for (int hf = 0; hf < 2; ++hf)
        #pragma unroll
        for (int u = 0; u < 4; ++u)
            #pragma unroll
            for (int r = 0; r < 4; ++r)
                pc[(size_t)(hf * 16 + quad * 4 + r) * FOUT + fw + u * 16 + n] = acc[hf][u][r];
}

// ------ Kernel 3: combine partials, normalize, elu ------
__global__ __launch_bounds__(256) void k_fin(const float* __restrict__ part,
                                             const float* __restrict__ psum,
                                             float* __restrict__ out, int C) {
    const int g = blockIdx.x * 256 + threadIdx.x;
    const int i = g >> 6;
    const size_t s4 = (size_t)NN * FOUT / 4;
    float4 a = ((const float4*)part)[g];
    float s = psum[i];
    for (int c = 1; c < C; ++c) {
        float4 bb = ((const float4*)part)[g + (size_t)c * s4];
        a.x += bb.x; a.y += bb.y; a.z += bb.z; a.w += bb.w;
        s += psum[(size_t)c * NN + i];
    }
    const float inv = 1.0f / s;
    a.x *= inv; a.y *= inv; a.z *= inv; a.w *= inv;
    a.x = a.x > 0.f ? a.x : __expf(a.x) - 1.f;
    a.y = a.y > 0.f ? a.y : __expf(a.y) - 1.f;
    a.z = a.z > 0.f ? a.z : __expf(a.z) - 1.f;
    a.w = a.w > 0.f ? a.w : __expf(a.w) - 1.f;
    ((float4*)out)[g] = a;
}

extern "C" void kernel_launch(void* const* d_in, const int* in_sizes, int n_in,
                              void* d_out, int out_size, void* d_ws, size_t ws_size,
                              hipStream_t stream) {
    const int*   adj = (const int*)  d_in[0];
    const float* h   = (const float*)d_in[1];
    const float* W   = (const float*)d_in[2];
    const float* b   = (const float*)d_in[3];
    const float* a1  = (const float*)d_in[4];
    const float* a2  = (const float*)d_in[5];
    const float* ab  = (const float*)d_in[6];
    float* out = (float*)d_out;

    const int C = CJ;

    float* fs   = (float*)d_ws;
    float* fd   = fs + NN;
    float* psum = fd + NN;
    float* part = psum + (size_t)C * NN;
    u16*   Wt   = (u16*)(part + (size_t)C * NN * FOUT);
    u16*   whT  = Wt + (size_t)FOUT * FIN;
    u64*   bits = (u64*)(whT + (size_t)NN * FOUT);

    k_wt  <<<dim3(FOUT / 64, FIN / 64), 256, 0, stream>>>(W, Wt, fs, fd);
    k_pb  <<<512 + NN / 2, 256, 0, stream>>>(h, Wt, b, a1, a2, adj, whT, fs, fd, bits);
    k_attn<<<dim3(NN / BI, CJ), 256, 0, stream>>>((const u32*)bits, whT, fs, fd, ab, part, psum);
    k_fin <<<(NN * FOUT / 4) / 256, 256, 0, stream>>>(part, psum, out, C);
}